// Round 1
// baseline (215.547 us; speedup 1.0000x reference)
//
#include <hip/hip_runtime.h>

// Problem constants
#define HWp    1024          // patches per image (32*32)
#define NPATCH 4096          // B * HWp
#define NCH    65            // 64 conv channels + 1 temperature channel
#define WSTR   66            // padded stride of transposed weight rows
#define KDIM   4096          // 64 ci * 8 * 8

// Workspace layout (float offsets)
#define WT_OFF    0u         // [4096][66] folded transposed weights
#define BIASP_OFF 270336u    // [64] folded conv biases
#define WSUM_OFF  270400u    // [64] channel-sum of conv2_w
#define MISC_OFF  270464u    // [0]=bias_t, [1]=sum(conv2_b)
#define S_OFF     270480u    // [4096] channel-sum s
#define INVT_OFF  274576u    // [4096] 1/(0.025+t)
#define PART_OFF  278672u    // [KS][66][4096] partial conv sums

// ---------------------------------------------------------------------------
// Prep: fold BN into conv weights/biases, transpose weights to [k][ch],
// compute wsum (channel sum of the 1x1 conv) and scalar biases.
// ---------------------------------------------------------------------------
__global__ void prep_kernel(
    const float* __restrict__ conv1_w, const float* __restrict__ conv1_b,
    const float* __restrict__ g,  const float* __restrict__ bb,
    const float* __restrict__ m,  const float* __restrict__ v,
    const float* __restrict__ conv2_w, const float* __restrict__ conv2_b,
    const float* __restrict__ tconv_w, const float* __restrict__ tconv_b,
    const float* __restrict__ tg, const float* __restrict__ tb,
    const float* __restrict__ tm, const float* __restrict__ tv,
    float* __restrict__ ws)
{
    float* Wt = ws + WT_OFF;
    if (blockIdx.x < 16) {
        int k = blockIdx.x * 256 + threadIdx.x;   // 0..4095
        float At = tg[0] / sqrtf(tv[0] + 1e-5f);
        #pragma unroll 8
        for (int c = 0; c < 64; ++c) {
            float A = g[c] / sqrtf(v[c] + 1e-5f);
            Wt[(size_t)k * WSTR + c] = A * conv1_w[(size_t)c * KDIM + k];
        }
        Wt[(size_t)k * WSTR + 64] = At * tconv_w[k];
        Wt[(size_t)k * WSTR + 65] = 0.0f;
    } else {
        int t = threadIdx.x;
        if (t < 64) {
            float A = g[t] / sqrtf(v[t] + 1e-5f);
            ws[BIASP_OFF + t] = A * (conv1_b[t] - m[t]) + bb[t];
            float s = 0.f;
            for (int co = 0; co < 64; ++co) s += conv2_w[co * 64 + t];
            ws[WSUM_OFF + t] = s;
        } else if (t == 64) {
            float At = tg[0] / sqrtf(tv[0] + 1e-5f);
            ws[MISC_OFF + 0] = At * (tconv_b[0] - tm[0]) + tb[0];
            float bs = 0.f;
            for (int c = 0; c < 64; ++c) bs += conv2_b[c];
            ws[MISC_OFF + 1] = bs;
        }
    }
}

// ---------------------------------------------------------------------------
// Patch conv, fp32. Block = 256 threads = 4 waves; each lane owns ONE patch
// (64 patches / block). Each wave handles a disjoint ci-range so weight
// addresses are wave-uniform -> s_load (scalar) weight traffic, zero
// LDS/VMEM per FMA. K is also split over blockIdx.y (KS chunks); per-block
// cross-wave reduce via LDS, then partials to ws.
// ---------------------------------------------------------------------------
__global__ __launch_bounds__(256, 2) void conv_kernel(
    const float* __restrict__ x, const float* __restrict__ ws_ro,
    float* __restrict__ partial, int ciPerWave)
{
    __shared__ float red[4][33][64];
    const float* Wt = ws_ro + WT_OFF;
    int t    = threadIdx.x;
    int wv   = __builtin_amdgcn_readfirstlane(t >> 6);  // wave id, forced SGPR
    int lane = t & 63;
    int mb   = blockIdx.x;       // 64 M-blocks of 64 patches
    int kb   = blockIdx.y;       // KS K-chunks
    int gp   = mb * 64 + lane;   // global patch id
    int b    = gp >> 10;
    int py   = (gp >> 5) & 31;
    int px   = gp & 31;
    int ci0  = (kb * 4 + wv) * ciPerWave;

    float acc[NCH];
    #pragma unroll
    for (int c = 0; c < NCH; ++c) acc[c] = 0.f;

    // x[((b*64+ci)*256 + (py*8+ky))*256 + px*8 + kx]
    const float* xbase = x + ((size_t)(b * 64) * 256 + py * 8) * 256 + px * 8;

    for (int cii = 0; cii < ciPerWave; ++cii) {
        int ci = ci0 + cii;
        const float* xc = xbase + (size_t)ci * 65536;
        #pragma unroll 2
        for (int ky = 0; ky < 8; ++ky) {
            const float4* xr = (const float4*)(xc + ky * 256);
            float4 a0 = xr[0];
            float4 a1 = xr[1];
            float xv[8];
            xv[0]=a0.x; xv[1]=a0.y; xv[2]=a0.z; xv[3]=a0.w;
            xv[4]=a1.x; xv[5]=a1.y; xv[6]=a1.z; xv[7]=a1.w;
            const float* wrow = Wt + (size_t)(ci * 8 + ky) * 8 * WSTR;
            #pragma unroll
            for (int kx = 0; kx < 8; ++kx) {
                const float* wk = wrow + kx * WSTR;   // wave-uniform
                float xk = xv[kx];
                #pragma unroll
                for (int c = 0; c < NCH; ++c)
                    acc[c] = fmaf(wk[c], xk, acc[c]);
            }
        }
    }

    // cross-wave reduce (two halves to stay under static LDS limit)
    #pragma unroll
    for (int half = 0; half < 2; ++half) {
        const int cbase = half * 33;
        const int cnt   = half ? 32 : 33;
        #pragma unroll
        for (int c = 0; c < 33; ++c)
            if (c < cnt) red[wv][c][lane] = acc[cbase + c];
        __syncthreads();
        for (int idx = t; idx < cnt * 64; idx += 256) {
            int c = idx >> 6, p = idx & 63;
            float s = red[0][c][p] + red[1][c][p] + red[2][c][p] + red[3][c][p];
            partial[((size_t)kb * WSTR + cbase + c) * NPATCH + mb * 64 + p] = s;
        }
        __syncthreads();
    }
}

// ---------------------------------------------------------------------------
// Finalize: sum K-chunks, add bias, ReLU, dot with wsum -> s; temperature
// channel -> invT = 1/(0.025+t).
// ---------------------------------------------------------------------------
__global__ void finalize_kernel(float* __restrict__ ws, int KS)
{
    const float* partial = ws + PART_OFF;
    int gp = blockIdx.x * 256 + threadIdx.x;   // 16 blocks -> 4096 patches
    float acc[NCH];
    #pragma unroll
    for (int c = 0; c < NCH; ++c) acc[c] = 0.f;
    for (int kb = 0; kb < KS; ++kb) {
        #pragma unroll
        for (int c = 0; c < NCH; ++c)
            acc[c] += partial[((size_t)kb * WSTR + c) * NPATCH + gp];
    }
    float s = ws[MISC_OFF + 1];
    #pragma unroll
    for (int c = 0; c < 64; ++c)
        s += ws[WSUM_OFF + c] * fmaxf(acc[c] + ws[BIASP_OFF + c], 0.f);
    float tval = fmaxf(acc[64] + ws[MISC_OFF + 0], 0.f);
    ws[S_OFF + gp]    = s;
    ws[INVT_OFF + gp] = 1.0f / (0.025f + tval);
}

// ---------------------------------------------------------------------------
// Fused 4-iteration softmax. One WAVE per query patch row; the 1024 logits
// live in 16 registers/lane; wave-shuffle reductions only (no barriers).
// Writes all 4 outputs; sim matrix never materialized.
// ---------------------------------------------------------------------------
__global__ __launch_bounds__(256) void softmax_kernel(
    const float* __restrict__ ws_ro, float* __restrict__ out)
{
    const float* sArr = ws_ro + S_OFF;
    const float* invT = ws_ro + INVT_OFF;
    int t    = threadIdx.x;
    int wv   = t >> 6;
    int lane = t & 63;
    int gp   = blockIdx.x * 4 + wv;   // 0..4095
    int b    = gp >> 10;
    int p    = gp & 1023;
    float sq = sArr[gp];
    float iT = invT[gp];
    const float4* srow = (const float4*)(sArr + (size_t)b * HWp);

    float L[16];
    #pragma unroll
    for (int c4 = 0; c4 < 4; ++c4) {
        float4 sv = srow[c4 * 64 + lane];
        int q0 = c4 * 256 + lane * 4;
        float d0 = sq - sv.x, d1 = sq - sv.y, d2 = sq - sv.z, d3 = sq - sv.w;
        L[c4*4+0] = -d0 * d0 * iT;
        L[c4*4+1] = -d1 * d1 * iT;
        L[c4*4+2] = -d2 * d2 * iT;
        L[c4*4+3] = -d3 * d3 * iT;
        if (q0 + 0 == p) L[c4*4+0] -= 1000.f * iT;
        if (q0 + 1 == p) L[c4*4+1] -= 1000.f * iT;
        if (q0 + 2 == p) L[c4*4+2] -= 1000.f * iT;
        if (q0 + 3 == p) L[c4*4+3] -= 1000.f * iT;
    }

    size_t rowOff = (size_t)gp * HWp;
    #pragma unroll 1
    for (int it = 0; it < 4; ++it) {
        float mx = L[0];
        #pragma unroll
        for (int j = 1; j < 16; ++j) mx = fmaxf(mx, L[j]);
        #pragma unroll
        for (int off = 32; off; off >>= 1)
            mx = fmaxf(mx, __shfl_xor(mx, off, 64));
        float e[16];
        float sum = 0.f;
        #pragma unroll
        for (int j = 0; j < 16; ++j) { e[j] = expf(L[j] - mx); sum += e[j]; }
        #pragma unroll
        for (int off = 32; off; off >>= 1)
            sum += __shfl_xor(sum, off, 64);
        float r = 1.0f / sum;
        #pragma unroll
        for (int j = 0; j < 16; ++j) e[j] *= r;   // e[] now holds p
        float4* orow = (float4*)(out + (size_t)it * NPATCH * HWp + rowOff);
        #pragma unroll
        for (int c4 = 0; c4 < 4; ++c4) {
            float4 o;
            o.x = e[c4*4+0]; o.y = e[c4*4+1]; o.z = e[c4*4+2]; o.w = e[c4*4+3];
            orow[c4 * 64 + lane] = o;
        }
        if (it < 3) {
            #pragma unroll
            for (int j = 0; j < 16; ++j)
                L[j] += iT * logf(1.0f - e[j] + 1e-45f);
        }
    }
}

// ---------------------------------------------------------------------------
extern "C" void kernel_launch(void* const* d_in, const int* in_sizes, int n_in,
                              void* d_out, int out_size, void* d_ws, size_t ws_size,
                              hipStream_t stream)
{
    (void)in_sizes; (void)n_in; (void)out_size;
    const float* x       = (const float*)d_in[0];
    const float* conv1_w = (const float*)d_in[1];
    const float* conv1_b = (const float*)d_in[2];
    const float* bn1_g   = (const float*)d_in[3];
    const float* bn1_b   = (const float*)d_in[4];
    const float* bn1_m   = (const float*)d_in[5];
    const float* bn1_v   = (const float*)d_in[6];
    const float* conv2_w = (const float*)d_in[7];
    const float* conv2_b = (const float*)d_in[8];
    const float* tconv_w = (const float*)d_in[9];
    const float* tconv_b = (const float*)d_in[10];
    const float* bnt_g   = (const float*)d_in[11];
    const float* bnt_b   = (const float*)d_in[12];
    const float* bnt_m   = (const float*)d_in[13];
    const float* bnt_v   = (const float*)d_in[14];

    float* ws  = (float*)d_ws;
    float* out = (float*)d_out;

    // Pick largest K-split whose partial buffer fits the workspace.
    int KS = 8;
    while (KS > 1 &&
           (size_t)(PART_OFF + (size_t)KS * WSTR * NPATCH) * 4 > ws_size)
        KS >>= 1;
    int ciPerWave = 64 / (KS * 4);

    prep_kernel<<<dim3(17), dim3(256), 0, stream>>>(
        conv1_w, conv1_b, bn1_g, bn1_b, bn1_m, bn1_v,
        conv2_w, conv2_b, tconv_w, tconv_b, bnt_g, bnt_b, bnt_m, bnt_v, ws);

    conv_kernel<<<dim3(64, KS), dim3(256), 0, stream>>>(
        x, ws, ws + PART_OFF, ciPerWave);

    finalize_kernel<<<dim3(16), dim3(256), 0, stream>>>(ws, KS);

    softmax_kernel<<<dim3(1024), dim3(256), 0, stream>>>(ws, out);
}